// Round 5
// baseline (94.674 us; speedup 1.0000x reference)
//
#include <hip/hip_runtime.h>
#include <hip/hip_bf16.h>

#define DDIM 4096
#define ADIM 21
#define WROWS 16              // rows per wave (= MFMA M)
#define NTHR 64               // 1 wave per block

typedef __attribute__((ext_vector_type(8))) short bf16x8;
typedef __attribute__((ext_vector_type(4))) float f32x4;

__device__ __forceinline__ unsigned pk2(float lo, float hi) {
    unsigned short a = __builtin_bit_cast(unsigned short, __float2bfloat16(lo));
    unsigned short b = __builtin_bit_cast(unsigned short, __float2bfloat16(hi));
    return (unsigned)a | ((unsigned)b << 16);
}

__device__ __forceinline__ bf16x8 cvt8(float4 a, float4 b) {
    union { unsigned u[4]; bf16x8 v; } r;
    r.u[0] = pk2(a.x, a.y); r.u[1] = pk2(a.z, a.w);
    r.u[2] = pk2(b.x, b.y); r.u[3] = pk2(b.z, b.w);
    return r.v;
}

// No LDS, no barriers: each lane loads its own MFMA fragment straight from
// global (A: lane row=l&15, k=(l>>4)*8..+8 -> two float4 = that lane's exact
// fragment; 64 lanes of one load instr touch 16 rows x 64B = 16 full lines).
// W fragments identical, L2-resident (344KB shared by all waves). The k-loop
// is pure load->cvt_pk->MFMA with zero sync points -> compiler pipelines it.
__global__ __launch_bounds__(NTHR, 1)
void fem_direct(const float* __restrict__ x,
                const float* __restrict__ v,
                const float* __restrict__ W,
                const float* __restrict__ bias,
                float* __restrict__ result,   // [B]
                float* __restrict__ out)      // [B][ADIM]
{
    const int lane = threadIdx.x;        // 0..63
    const int a0   = lane & 15;          // fragment row/col within 16
    const int kh   = (lane >> 4) * 8;    // k sub-offset within K=32
    const int rowbase = blockIdx.x * WROWS;

    const float* __restrict__ xp  = x + (size_t)(rowbase + a0) * DDIM + kh;
    const float* __restrict__ wp0 = W + (size_t)a0 * DDIM + kh;
    const bool hasb1 = (a0 < 5);
    // clamped-safe address; lanes a0>=5 never execute the b1 load
    const float* __restrict__ wp1 = W + (size_t)(hasb1 ? 16 + a0 : a0) * DDIM + kh;

    f32x4 acc0, acc1;
    {
        const float b0v = bias[a0];
        const float b1v = hasb1 ? bias[16 + a0] : 0.f;
        acc0 = (f32x4){b0v, b0v, b0v, b0v};
        acc1 = (f32x4){b1v, b1v, b1v, b1v};
    }

#pragma unroll 4
    for (int k0 = 0; k0 < DDIM; k0 += 32) {
        const float4 xa  = *(const float4*)(xp + k0);
        const float4 xb  = *(const float4*)(xp + k0 + 4);
        const float4 w0a = *(const float4*)(wp0 + k0);
        const float4 w0b = *(const float4*)(wp0 + k0 + 4);
        bf16x8 bf1;
        if (hasb1) {
            const float4 w1a = *(const float4*)(wp1 + k0);
            const float4 w1b = *(const float4*)(wp1 + k0 + 4);
            bf1 = cvt8(w1a, w1b);
        } else {
            bf1 = (bf16x8){0, 0, 0, 0, 0, 0, 0, 0};
        }
        const bf16x8 af  = cvt8(xa, xb);
        const bf16x8 bf0 = cvt8(w0a, w0b);
        acc0 = __builtin_amdgcn_mfma_f32_16x16x32_bf16(af, bf0, acc0, 0, 0, 0);
        acc1 = __builtin_amdgcn_mfma_f32_16x16x32_bf16(af, bf1, acc1, 0, 0, 0);
    }

    // Epilogue: C/D layout row=(lane>>4)*4+reg, col=lane&15 (verified layout).
    // Every out element written exactly once; result via 16-lane shfl reduce.
    const size_t growbase = (size_t)rowbase + (lane >> 4) * 4;
#pragma unroll
    for (int r = 0; r < 4; ++r) {
        const size_t row = growbase + r;
        const float o0 = acc0[r];
        out[row * ADIM + a0] = o0;
        float p = o0 * v[row * ADIM + a0];
        if (hasb1) {
            const float o1 = acc1[r];
            out[row * ADIM + 16 + a0] = o1;
            p += o1 * v[row * ADIM + 16 + a0];
        }
        p += __shfl_xor(p, 1);
        p += __shfl_xor(p, 2);
        p += __shfl_xor(p, 4);
        p += __shfl_xor(p, 8);
        if (a0 == 0) result[row] = p;
    }
}

extern "C" void kernel_launch(void* const* d_in, const int* in_sizes, int n_in,
                              void* d_out, int out_size, void* d_ws, size_t ws_size,
                              hipStream_t stream) {
    const float* x  = (const float*)d_in[0];
    const float* v  = (const float*)d_in[1];
    const float* W  = (const float*)d_in[2];
    const float* b  = (const float*)d_in[3];

    const int B = in_sizes[0] / DDIM;     // 16384

    float* result = (float*)d_out;        // [B]
    float* out    = (float*)d_out + B;    // [B][ADIM]

    fem_direct<<<dim3(B / WROWS), dim3(NTHR), 0, stream>>>(x, v, W, b, result, out);
}

// Round 6
// 55.941 us; speedup vs baseline: 1.6924x; 1.6924x over previous
//
#include <hip/hip_runtime.h>
#include <hip/hip_bf16.h>

#define DDIM 4096
#define ADIM 21
#define BM   64                 // rows per block
#define KC   128                // k per chunk
#define NCH  (DDIM / KC)        // 32
#define NTHR 256                // 4 waves

typedef __attribute__((ext_vector_type(8))) short bf16x8;
typedef __attribute__((ext_vector_type(4))) float f32x4;

// LDS: x tile [64][128] bf16 (16KB) x2, W tile [32][128] bf16 (8KB) x2 = 48KB
#define XOFF(b) ((b) * 16384)
#define WOFF(b) (32768 + (b) * 8192)

// row-major [row][k] bf16, row stride 256B; XOR-swizzle 16B granules
__device__ __forceinline__ int swz(int row, int kbyte) {
    return (row * 256 + kbyte) ^ ((row & 7) << 4);
}

__device__ __forceinline__ unsigned pk2(float lo, float hi) {
    unsigned short a = __builtin_bit_cast(unsigned short, __float2bfloat16(lo));
    unsigned short b = __builtin_bit_cast(unsigned short, __float2bfloat16(hi));
    return (unsigned)a | ((unsigned)b << 16);
}

// Schedule: 1 raw s_barrier per chunk (lgkmcnt(0) only — vmcnt NEVER drained,
// so global loads stay in flight across barriers, the §5 structural-stall fix).
// Each reg set (E/O) is issued 2 chunks before its ds_write -> ~2 compute
// phases of latency cover; compiler inserts the counted vmcnt at write_stage.
__global__ __launch_bounds__(NTHR, 1)
void fem_mfma(const float* __restrict__ x,
              const float* __restrict__ v,
              const float* __restrict__ W,
              const float* __restrict__ bias,
              float* __restrict__ result,   // [B]
              float* __restrict__ out)      // [B][ADIM]
{
    __shared__ char smem[49152];
    const int t = threadIdx.x;
    const int rowbase = blockIdx.x * BM;

    float4 xE[8], xO[8], wE[4], wO[4];

    auto issue = [&](int c, float4 (&xr)[8], float4 (&wr)[4]) {
        const float* xs = x + (size_t)(rowbase + (t >> 4)) * DDIM + c * KC + (t & 15) * 8;
#pragma unroll
        for (int j = 0; j < 4; ++j) {
            const float* s = xs + (size_t)j * 16 * DDIM;
            xr[2 * j]     = *(const float4*)s;
            xr[2 * j + 1] = *(const float4*)(s + 4);
        }
        const float* ws = W + (size_t)(t >> 4) * DDIM + c * KC + (t & 15) * 8;
        wr[0] = *(const float4*)ws;
        wr[1] = *(const float4*)(ws + 4);
        if (t < 80) {                       // W rows 16..20
            const float* w2 = W + (size_t)(16 + (t >> 4)) * DDIM + c * KC + (t & 15) * 8;
            wr[2] = *(const float4*)w2;
            wr[3] = *(const float4*)(w2 + 4);
        }
    };

    auto write_stage = [&](int buf, const float4 (&xr)[8], const float4 (&wr)[4]) {
        char* xb = smem + XOFF(buf);
        const int kg = t & 15;
#pragma unroll
        for (int j = 0; j < 4; ++j) {
            const int row = (t >> 4) + j * 16;
            uint4 g;
            g.x = pk2(xr[2 * j].x, xr[2 * j].y);
            g.y = pk2(xr[2 * j].z, xr[2 * j].w);
            g.z = pk2(xr[2 * j + 1].x, xr[2 * j + 1].y);
            g.w = pk2(xr[2 * j + 1].z, xr[2 * j + 1].w);
            *(uint4*)(xb + swz(row, kg * 16)) = g;
        }
        char* wb = smem + WOFF(buf);
        {
            uint4 g;
            g.x = pk2(wr[0].x, wr[0].y); g.y = pk2(wr[0].z, wr[0].w);
            g.z = pk2(wr[1].x, wr[1].y); g.w = pk2(wr[1].z, wr[1].w);
            *(uint4*)(wb + swz(t >> 4, kg * 16)) = g;
        }
        if (t < 80) {
            uint4 g;
            g.x = pk2(wr[2].x, wr[2].y); g.y = pk2(wr[2].z, wr[2].w);
            g.z = pk2(wr[3].x, wr[3].y); g.w = pk2(wr[3].z, wr[3].w);
            *(uint4*)(wb + swz(16 + (t >> 4), kg * 16)) = g;
        }
    };

    const int lane = t & 63;
    const int wv   = t >> 6;            // wave id, owns 16 rows
    const int a0   = lane & 15;
    const int kh   = (lane >> 4) * 8;

    f32x4 acc0, acc1;
    {
        const float ba0 = bias[a0];
        const float ba1 = (a0 < 5) ? bias[16 + a0] : 0.f;
        acc0 = (f32x4){ba0, ba0, ba0, ba0};
        acc1 = (f32x4){ba1, ba1, ba1, ba1};
    }

    auto compute = [&](int buf) {
        const char* xb = smem + XOFF(buf);
        const char* wb = smem + WOFF(buf);
        const int rowA = wv * 16 + (lane & 15);
#pragma unroll
        for (int k0 = 0; k0 < KC; k0 += 32) {
            bf16x8 a  = *(const bf16x8*)(xb + swz(rowA,    (k0 + kh) * 2));
            bf16x8 b0 = *(const bf16x8*)(wb + swz(a0,      (k0 + kh) * 2));
            bf16x8 b1 = *(const bf16x8*)(wb + swz(16 + a0, (k0 + kh) * 2));
            acc0 = __builtin_amdgcn_mfma_f32_16x16x32_bf16(a, b0, acc0, 0, 0, 0);
            acc1 = __builtin_amdgcn_mfma_f32_16x16x32_bf16(a, b1, acc1, 0, 0, 0);
        }
    };

    // Raw barrier: drain LDS ops only; global loads stay in flight.
    auto barrier = [&]() {
        asm volatile("s_waitcnt lgkmcnt(0)" ::: "memory");
        __builtin_amdgcn_s_barrier();
        __builtin_amdgcn_sched_barrier(0);   // rule #18 insurance
    };

    // ---- prologue: zero W rows 21..31 (both buffers, never rewritten) ----
    if (t < 176) {
        const int row = 21 + (t >> 4), kg = t & 15;
        const uint4 z = {0, 0, 0, 0};
        *(uint4*)(smem + WOFF(0) + swz(row, kg * 16)) = z;
        *(uint4*)(smem + WOFF(1) + swz(row, kg * 16)) = z;
    }
    issue(0, xE, wE);
    issue(1, xO, wO);
    write_stage(0, xE, wE);       // chunk 0 -> buf0 (one-time vmcnt stall)
    issue(2, xE, wE);             // chunk 2 in flight
    barrier();                    // buf0 ready

    // ---- main loop: 2 chunks/iter, 1 barrier/chunk ----
    for (int c = 0; c <= NCH - 4; c += 2) {
        write_stage(1, xO, wO);               // chunk c+1 (issued 1 iter ago)
        issue(c + 3, xO, wO);                 // c+3 <= NCH-1 always here
        compute(0);                           // chunk c
        barrier();                            // buf1 ready, buf0 free
        write_stage(0, xE, wE);               // chunk c+2
        if (c + 4 < NCH) issue(c + 4, xE, wE);
        compute(1);                           // chunk c+1
        barrier();                            // buf0 ready, buf1 free
    }
    // tail: buf0 has chunk NCH-2, xO holds chunk NCH-1
    write_stage(1, xO, wO);
    compute(0);                               // chunk NCH-2
    barrier();
    compute(1);                               // chunk NCH-1

    // ---- epilogue: C/D layout row=(lane>>4)*4+reg, col=lane&15 ----
    // Every output element written exactly once (no atomics, no memset).
    const size_t growbase = (size_t)rowbase + wv * 16 + (lane >> 4) * 4;
#pragma unroll
    for (int r = 0; r < 4; ++r) {
        const size_t row = growbase + r;
        const float o0 = acc0[r];
        out[row * ADIM + a0] = o0;
        float p = o0 * v[row * ADIM + a0];
        if (a0 < 5) {
            const float o1 = acc1[r];
            out[row * ADIM + 16 + a0] = o1;
            p += o1 * v[row * ADIM + 16 + a0];
        }
        p += __shfl_xor(p, 1);
        p += __shfl_xor(p, 2);
        p += __shfl_xor(p, 4);
        p += __shfl_xor(p, 8);
        if (a0 == 0) result[row] = p;
    }
}

extern "C" void kernel_launch(void* const* d_in, const int* in_sizes, int n_in,
                              void* d_out, int out_size, void* d_ws, size_t ws_size,
                              hipStream_t stream) {
    const float* x  = (const float*)d_in[0];
    const float* v  = (const float*)d_in[1];
    const float* W  = (const float*)d_in[2];
    const float* b  = (const float*)d_in[3];

    const int B = in_sizes[0] / DDIM;     // 16384

    float* result = (float*)d_out;        // [B]
    float* out    = (float*)d_out + B;    // [B][ADIM]

    fem_mfma<<<dim3(B / BM), dim3(NTHR), 0, stream>>>(x, v, W, b, result, out);
}